// Round 6
// baseline (752.257 us; speedup 1.0000x reference)
//
#include <hip/hip_runtime.h>
#include <hip/hip_bf16.h>
#include <cstdint>

// Instance: B=4,S=4096 -> T=16384, D=1024, E=8, H=1024, top_k=2. f32 in/out.
#define T_TOK 16384
#define DDIM  1024

typedef __attribute__((ext_vector_type(8))) short bf16x8;
typedef __attribute__((ext_vector_type(4))) float f32x4;

__device__ __forceinline__ unsigned short f2bf(float f) {
  unsigned u = __builtin_bit_cast(unsigned, f);
  return (unsigned short)((u + 0x7fffu + ((u >> 16) & 1u)) >> 16);  // RNE
}
__device__ __forceinline__ unsigned pk2(float a, float b) {
  return (unsigned)f2bf(a) | ((unsigned)f2bf(b) << 16);
}
__device__ __forceinline__ void gload16(const void* g, void* l) {
  typedef __attribute__((address_space(1))) const unsigned int gu32;
  typedef __attribute__((address_space(3))) unsigned int lu32;
  __builtin_amdgcn_global_load_lds((gu32*)g, (lu32*)l, 16, 0, 0);
}

#define SBAR()                        \
  __builtin_amdgcn_sched_barrier(0);  \
  __builtin_amdgcn_s_barrier();       \
  __builtin_amdgcn_sched_barrier(0)
#define WAIT_VM6()                                        \
  asm volatile("s_waitcnt vmcnt(6)" ::: "memory");        \
  __builtin_amdgcn_sched_barrier(0)
#define WAIT_VM0()                                        \
  asm volatile("s_waitcnt vmcnt(0)" ::: "memory");        \
  __builtin_amdgcn_sched_barrier(0)
#define WAIT_LGKM0()                                      \
  asm volatile("s_waitcnt lgkmcnt(0)" ::: "memory");      \
  __builtin_amdgcn_sched_barrier(0)

// ---------------------------------------------------------------------------
// Transpose-convert weights f32->bf16 (unchanged, verified).
// ---------------------------------------------------------------------------
__global__ __launch_bounds__(256) void convert_k(
    const float* __restrict__ gw, const float* __restrict__ pw,
    const float* __restrict__ ow, char* __restrict__ wg,
    char* __restrict__ wp, char* __restrict__ wo) {
  __shared__ float t[64][65];
  const int z = blockIdx.z;
  const int arr = z >> 3, e = z & 7;
  const float* src = (arr == 0 ? gw : arr == 1 ? pw : ow) + ((long)e << 20);
  char* dst = (arr == 0 ? wg : arr == 1 ? wp : wo) + ((long)e << 21);
  const int r0 = blockIdx.x * 64, c0 = blockIdx.y * 64;
  const int row = threadIdx.x >> 2, q = threadIdx.x & 3;
  const float4* sp = (const float4*)(src + (long)(r0 + row) * 1024 + c0 + q * 16);
  float4 v0 = sp[0], v1 = sp[1], v2 = sp[2], v3 = sp[3];
  float* tr = &t[row][q * 16];
  tr[0]=v0.x; tr[1]=v0.y; tr[2]=v0.z; tr[3]=v0.w;
  tr[4]=v1.x; tr[5]=v1.y; tr[6]=v1.z; tr[7]=v1.w;
  tr[8]=v2.x; tr[9]=v2.y; tr[10]=v2.z; tr[11]=v2.w;
  tr[12]=v3.x; tr[13]=v3.y; tr[14]=v3.z; tr[15]=v3.w;
  __syncthreads();
  const int cl = row, rq = q;
  uint4 o0, o1;
  o0.x = pk2(t[rq*16+ 0][cl], t[rq*16+ 1][cl]);
  o0.y = pk2(t[rq*16+ 2][cl], t[rq*16+ 3][cl]);
  o0.z = pk2(t[rq*16+ 4][cl], t[rq*16+ 5][cl]);
  o0.w = pk2(t[rq*16+ 6][cl], t[rq*16+ 7][cl]);
  o1.x = pk2(t[rq*16+ 8][cl], t[rq*16+ 9][cl]);
  o1.y = pk2(t[rq*16+10][cl], t[rq*16+11][cl]);
  o1.z = pk2(t[rq*16+12][cl], t[rq*16+13][cl]);
  o1.w = pk2(t[rq*16+14][cl], t[rq*16+15][cl]);
  char* dp = dst + (long)(c0 + cl) * 2048 + (long)(r0 + rq * 16) * 2;
  *(uint4*)dp = o0;
  *(uint4*)(dp + 16) = o1;
}

// ---------------------------------------------------------------------------
// Router (unchanged, verified).
// ---------------------------------------------------------------------------
__global__ __launch_bounds__(256) void router_k(
    const float* __restrict__ x, const float* __restrict__ gatew,
    float* __restrict__ logitsOut, float4* __restrict__ route,
    float* __restrict__ accum, unsigned short* __restrict__ xbo) {
  __shared__ float accB[16];
  const int tid = threadIdx.x;
  if (tid < 16) accB[tid] = 0.f;
  __syncthreads();
  const int lane = tid & 63;
  const int gwave = blockIdx.x * 4 + (tid >> 6);

  for (int g = gwave; g < 4096; g += 1024) {
    const int t0 = g * 4;
    float s[4][8];
#pragma unroll
    for (int tt = 0; tt < 4; ++tt)
#pragma unroll
      for (int e = 0; e < 8; ++e) s[tt][e] = 0.f;

    for (int i = 0; i < 16; ++i) {
      int d = lane + i * 64;
      float4 w0 = *(const float4*)(gatew + d * 8);
      float4 w1 = *(const float4*)(gatew + d * 8 + 4);
#pragma unroll
      for (int tt = 0; tt < 4; ++tt) {
        float xv = x[(long)(t0 + tt) * DDIM + d];
        if (xbo) xbo[(long)(t0 + tt) * DDIM + d] = f2bf(xv);
        s[tt][0] += xv * w0.x; s[tt][1] += xv * w0.y;
        s[tt][2] += xv * w0.z; s[tt][3] += xv * w0.w;
        s[tt][4] += xv * w1.x; s[tt][5] += xv * w1.y;
        s[tt][6] += xv * w1.z; s[tt][7] += xv * w1.w;
      }
    }
#pragma unroll
    for (int m = 1; m < 64; m <<= 1)
#pragma unroll
      for (int tt = 0; tt < 4; ++tt)
#pragma unroll
        for (int e = 0; e < 8; ++e) s[tt][e] += __shfl_xor(s[tt][e], m);

    float psum[8];
#pragma unroll
    for (int e = 0; e < 8; ++e) psum[e] = 0.f;
    int i1a[4], i2a[4];
    float w1a[4], w2a[4];
#pragma unroll
    for (int tt = 0; tt < 4; ++tt) {
      float mx = s[tt][0];
#pragma unroll
      for (int e = 1; e < 8; ++e) mx = fmaxf(mx, s[tt][e]);
      float pe[8], Z = 0.f;
#pragma unroll
      for (int e = 0; e < 8; ++e) { pe[e] = __expf(s[tt][e] - mx); Z += pe[e]; }
      float inv = 1.f / Z;
#pragma unroll
      for (int e = 0; e < 8; ++e) { pe[e] *= inv; psum[e] += pe[e]; }
      int i1 = 0; float p1 = pe[0];
#pragma unroll
      for (int e = 1; e < 8; ++e) if (pe[e] > p1) { p1 = pe[e]; i1 = e; }
      int i2 = -1; float p2 = -1.f;
#pragma unroll
      for (int e = 0; e < 8; ++e)
        if (e != i1 && pe[e] > p2) { p2 = pe[e]; i2 = e; }
      float wsum = p1 + p2;
      i1a[tt] = i1; i2a[tt] = i2;
      w1a[tt] = p1 / wsum; w2a[tt] = p2 / wsum;
    }
    if (lane < 32) {
      int tt = lane >> 3, e = lane & 7;
      logitsOut[(t0 + tt) * 8 + e] = s[tt][e];
    }
    if (lane < 32 && (lane & 7) == 0) {
      int tt = lane >> 3;
      float4 rr;
      rr.x = w1a[tt]; rr.y = w2a[tt];
      rr.z = __int_as_float(i1a[tt]); rr.w = __int_as_float(i2a[tt]);
      route[t0 + tt] = rr;
    }
    if (lane < 8) {
      float c = 0.f;
#pragma unroll
      for (int tt = 0; tt < 4; ++tt)
        c += (float)(i1a[tt] == lane) + (float)(i2a[tt] == lane);
      atomicAdd(&accB[lane], psum[lane]);
      atomicAdd(&accB[8 + lane], c);
    }
  }
  __syncthreads();
  if (tid < 16) atomicAdd(&accum[tid], accB[tid]);
}

// ---------------------------------------------------------------------------
__global__ void offsets_k(const float* __restrict__ accum,
                          int* __restrict__ offs, int* __restrict__ cursor) {
  if (threadIdx.x == 0) {
    int c = 0;
#pragma unroll
    for (int e = 0; e < 8; ++e) {
      offs[e] = c; cursor[e] = c;
      c += (int)(accum[8 + e] + 0.5f);
    }
    offs[8] = c;
  }
}

__global__ __launch_bounds__(256) void scatter_k(
    const float4* __restrict__ route, int* __restrict__ cursor,
    int* __restrict__ list, float* __restrict__ wsl) {
  int t = blockIdx.x * 256 + threadIdx.x;
  float4 rr = route[t];
  int i1 = __float_as_int(rr.z), i2 = __float_as_int(rr.w);
  int s1 = atomicAdd(&cursor[i1], 1);
  list[s1] = t; wsl[s1] = rr.x;
  int s2 = atomicAdd(&cursor[i2], 1);
  list[s2] = t; wsl[s2] = rr.y;
}

// ---------------------------------------------------------------------------
// Pass 1 grouped GEMM. Single-barrier-per-K-step dbuf pipeline:
//   SBAR; STAGE(k+1 -> buf^1); vmcnt(6); FRAGS(cur); lgkm(0); MFMA
// No barrier between lgkm and MFMA -> wave-staggered LDS/MFMA overlap.
// XCD swizzle: e = x&7 (all tiles of expert e on XCD e; weight panel L2-hot).
// ---------------------------------------------------------------------------
template <int XB>
__global__ __launch_bounds__(512) void pass1_k(
    const float* __restrict__ x, const unsigned short* __restrict__ xb,
    const char* __restrict__ wg, const char* __restrict__ wp,
    const int* __restrict__ list, const float* __restrict__ wsl,
    const int* __restrict__ offs, char* __restrict__ hw) {
  __shared__ __align__(16) char Al[2][16384];
  __shared__ __align__(16) char Bgl[2][16384];
  __shared__ __align__(16) char Bpl[2][16384];
  const int e = blockIdx.x & 7, tile = blockIdx.x >> 3;  // XCD-aware decode
  const int s0 = offs[e], s1 = offs[e + 1];
  const int start = s0 + tile * 128;
  if (start >= s1) return;
  const int valid = min(128, s1 - start);
  const int chunk = blockIdx.y;  // h-cols chunk*128
  const int tid = threadIdx.x, lane = tid & 63, wid = tid >> 6;

  const int l8 = lane >> 3, seg = lane & 7;
  const unsigned inrow = ((unsigned)(seg * 16)) ^ (((unsigned)l8) << 4);
  const int br0 = wid * 16 + l8, br1 = br0 + 8;
  const long wbase = ((long)e << 21) + ((long)(chunk * 128) << 11);
  const char* gsrc0 = wg + wbase + ((long)br0 << 11) + inrow;
  const char* gsrc1 = wg + wbase + ((long)br1 << 11) + inrow;
  const char* psrc0 = wp + wbase + ((long)br0 << 11) + inrow;
  const char* psrc1 = wp + wbase + ((long)br1 << 11) + inrow;
  const unsigned ld0 = (unsigned)(wid * 2048), ld1 = ld0 + 1024;

  const int tokA0 = list[start + min(br0, valid - 1)];
  const int tokA1 = list[start + min(br1, valid - 1)];
  const char* asrc0 = (const char*)xb + ((long)tokA0 << 11) + inrow;
  const char* asrc1 = (const char*)xb + ((long)tokA1 << 11) + inrow;
  // XB=0 fallback staging
  const int sr = tid >> 2, q = tid & 3;
  const int tokS = list[start + min(sr, valid - 1)];
  const float* axp = x + (long)tokS * DDIM + q * 16;
  const unsigned swz = ((unsigned)(sr & 7)) << 4;
  const unsigned sb = (unsigned)(sr * 128 + q * 32);

  f32x4 aG[4][2], aP[4][2];
#pragma unroll
  for (int f = 0; f < 4; ++f)
#pragma unroll
    for (int j = 0; j < 2; ++j) {
      aG[f][j] = (f32x4){0.f, 0.f, 0.f, 0.f};
      aP[f][j] = (f32x4){0.f, 0.f, 0.f, 0.f};
    }

  const int col = lane & 15, kg = lane >> 4;
  const int mb = (wid >> 2) * 64, nb = (wid & 3) * 32;

#define P1_STAGE(kb, buf)                                     \
  {                                                           \
    long ko = (long)(kb) << 7;                                \
    gload16(asrc0 + ko, &Al[buf][ld0]);                       \
    gload16(asrc1 + ko, &Al[buf][ld1]);                       \
    gload16(gsrc0 + ko, &Bgl[buf][ld0]);                      \
    gload16(gsrc1 + ko, &Bgl[buf][ld1]);                      \
    gload16(psrc0 + ko, &Bpl[buf][ld0]);                      \
    gload16(psrc1 + ko, &Bpl[buf][ld1]);                      \
  }
#define P1_FRAGS(cur)                                                      \
  bf16x8 af[2][4], bg2[2][2], bp2[2][2];                                   \
  _Pragma("unroll") for (int ks = 0; ks < 2; ++ks) {                       \
    _Pragma("unroll") for (int f = 0; f < 4; ++f) {                        \
      int r = mb + f * 16 + col;                                           \
      af[ks][f] = *(const bf16x8*)(                                        \
          &Al[cur][0] + ((unsigned)(r * 128 + ks * 64 + kg * 16) ^         \
                         (((unsigned)r & 7u) << 4)));                      \
    }                                                                      \
    _Pragma("unroll") for (int j = 0; j < 2; ++j) {                        \
      int n = nb + j * 16 + col;                                           \
      unsigned off = (unsigned)(n * 128 + ks * 64 + kg * 16) ^             \
                     (((unsigned)n & 7u) << 4);                            \
      bg2[ks][j] = *(const bf16x8*)(&Bgl[cur][0] + off);                   \
      bp2[ks][j] = *(const bf16x8*)(&Bpl[cur][0] + off);                   \
    }                                                                      \
  }
#define P1_MFMA()                                                          \
  __builtin_amdgcn_s_setprio(1);                                           \
  _Pragma("unroll") for (int ks = 0; ks < 2; ++ks)                         \
  _Pragma("unroll") for (int f = 0; f < 4; ++f)                            \
  _Pragma("unroll") for (int j = 0; j < 2; ++j) {                          \
    aG[f][j] = __builtin_amdgcn_mfma_f32_16x16x32_bf16(                    \
        af[ks][f], bg2[ks][j], aG[f][j], 0, 0, 0);                         \
    aP[f][j] = __builtin_amdgcn_mfma_f32_16x16x32_bf16(                    \
        af[ks][f], bp2[ks][j], aP[f][j], 0, 0, 0);                         \
  }                                                                        \
  __builtin_amdgcn_s_setprio(0)

  if (XB) {
    P1_STAGE(0, 0);
#pragma unroll 1
    for (int kb = 0; kb < 16; ++kb) {
      const int cur = kb & 1;
      SBAR();  // all waves done reading buf[cur^1] (last iter) -> refill ok
      if (kb < 15) {
        P1_STAGE(kb + 1, cur ^ 1);
        WAIT_VM6();  // stage kb landed; the 6 just-issued stay in flight
      } else {
        WAIT_VM0();
      }
      P1_FRAGS(cur);
      WAIT_LGKM0();
      P1_MFMA();  // no barrier before MFMA: wave-staggered overlap
    }
  } else {
    // legacy 2-phase fallback (verified round 3)
    for (int kb = 0; kb < 16; ++kb) {
      __syncthreads();
      {
        const float4* ap = (const float4*)(axp + kb * 64);
        float4 v0 = ap[0], v1 = ap[1], v2 = ap[2], v3 = ap[3];
        uint4 w0, w1;
        w0.x = pk2(v0.x, v0.y); w0.y = pk2(v0.z, v0.w);
        w0.z = pk2(v1.x, v1.y); w0.w = pk2(v1.z, v1.w);
        w1.x = pk2(v2.x, v2.y); w1.y = pk2(v2.z, v2.w);
        w1.z = pk2(v3.x, v3.y); w1.w = pk2(v3.z, v3.w);
        *(uint4*)(&Al[0][0] + (sb ^ swz)) = w0;
        *(uint4*)(&Al[0][0] + ((sb + 16) ^ swz)) = w1;
        long ko = (long)kb << 7;
        gload16(gsrc0 + ko, &Bgl[0][ld0]);
        gload16(gsrc1 + ko, &Bgl[0][ld1]);
        gload16(psrc0 + ko, &Bpl[0][ld0]);
        gload16(psrc1 + ko, &Bpl[0][ld1]);
      }
      __syncthreads();
      P1_FRAGS(0);
      P1_MFMA();
    }
  }

  const int rg = lane >> 4;
#pragma unroll
  for (int f = 0; f < 4; ++f) {
#pragma unroll
    for (int r = 0; r < 4; ++r) {
      int ml = mb + f * 16 + rg * 4 + r;
      if (ml < valid) {
        int slot = start + ml;
        float wv = wsl[slot];
#pragma unroll
        for (int j = 0; j < 2; ++j) {
          float g = aG[f][j][r], p = aP[f][j][r];
          float h = g * (p / (1.f + __expf(-p))) * wv;
          int hc = chunk * 128 + nb + j * 16 + col;
          *(unsigned short*)(hw + (((long)slot << 11) + (hc << 1))) = f2bf(h);
        }
      }
    }
  }
}

// ---------------------------------------------------------------------------
// Pass 2 grouped GEMM — same single-barrier pipeline + XCD decode.
// Tile 128 x 256; atomicAdd epilogue.
// ---------------------------------------------------------------------------
__global__ __launch_bounds__(512) void pass2_k(
    const char* __restrict__ hw, const char* __restrict__ wo,
    const int* __restrict__ list, const int* __restrict__ offs,
    float* __restrict__ out) {
  __shared__ __align__(16) char Al[2][16384];
  __shared__ __align__(16) char Bl[2][32768];
  const int e = blockIdx.x & 7, tile = blockIdx.x >> 3;  // XCD-aware decode
  const int s0 = offs[e], s1 = offs[e + 1];
  const int start = s0 + tile * 128;
  if (start >= s1) return;
  const int valid = min(128, s1 - start);
  const int chunk = blockIdx.y;  // d-cols chunk*256
  const int tid = threadIdx.x, lane = tid & 63, wid = tid >> 6;

  const int l8 = lane >> 3, seg = lane & 7;
  const unsigned inrow = ((unsigned)(seg * 16)) ^ (((unsigned)l8) << 4);
  const int ar0 = wid * 16 + l8, ar1 = ar0 + 8;
  const char* asrc0 = hw + ((long)(start + min(ar0, valid - 1)) << 11) + inrow;
  const char* asrc1 = hw + ((long)(start + min(ar1, valid - 1)) << 11) + inrow;
  const unsigned lda0 = (unsigned)(wid * 2048), lda1 = lda0 + 1024;
  const long wobase = ((long)e << 21) + ((long)(chunk * 256) << 11);
  const char* bsrc[4];
  unsigned ldb[4];
#pragma unroll
  for (int i = 0; i < 4; ++i) {
    int n = wid * 32 + i * 8 + l8;
    bsrc[i] = wo + wobase + ((long)n << 11) + inrow;
    ldb[i] = (unsigned)(wid * 4096 + i * 1024);
  }

  f32x4 acc[4][4];
#pragma unroll
  for (int f = 0; f < 4; ++f)
#pragma unroll
    for (int j = 0; j < 4; ++j) acc[f][j] = (f32x4){0.f, 0.f, 0.f, 0.f};

  const int col = lane & 15, kg = lane >> 4;
  const int mb = (wid >> 2) * 64, nb = (wid & 3) * 64;

#define P2_STAGE(kb, buf)                                     \
  {                                                           \
    long ko = (long)(kb) << 7;                                \
    gload16(asrc0 + ko, &Al[buf][lda0]);                      \
    gload16(asrc1 + ko, &Al[buf][lda1]);                      \
    gload16(bsrc[0] + ko, &Bl[buf][ldb[0]]);                  \
    gload16(bsrc[1] + ko, &Bl[buf][ldb[1]]);                  \
    gload16(bsrc[2] + ko, &Bl[buf][ldb[2]]);                  \
    gload16(bsrc[3] + ko, &Bl[buf][ldb[3]]);                  \
  }
#define P2_FRAGS(cur)                                                      \
  bf16x8 af[2][4], bf4[2][4];                                              \
  _Pragma("unroll") for (int ks = 0; ks < 2; ++ks) {                       \
    _Pragma("unroll") for (int f = 0; f < 4; ++f) {                        \
      int r = mb + f * 16 + col;                                           \
      af[ks][f] = *(const bf16x8*)(                                        \
          &Al[cur][0] + ((unsigned)(r * 128 + ks * 64 + kg * 16) ^         \
                         (((unsigned)r & 7u) << 4)));                      \
    }                                                                      \
    _Pragma("unroll") for (int j = 0; j < 4; ++j) {                        \
      int n = nb + j * 16 + col;                                           \
      bf4[ks][j] = *(const bf16x8*)(                                       \
          &Bl[cur][0] + ((unsigned)(n * 128 + ks * 64 + kg * 16) ^         \
                         (((unsigned)n & 7u) << 4)));                      \
    }                                                                      \
  }
#define P2_MFMA()                                                          \
  __builtin_amdgcn_s_setprio(1);                                           \
  _Pragma("unroll") for (int ks = 0; ks < 2; ++ks)                         \
  _Pragma("unroll") for (int f = 0; f < 4; ++f)                            \
  _Pragma("unroll") for (int j = 0; j < 4; ++j)                            \
    acc[f][j] = __builtin_amdgcn_mfma_f32_16x16x32_bf16(                   \
        af[ks][f], bf4[ks][j], acc[f][j], 0, 0, 0);                        \
  __builtin_amdgcn_s_setprio(0)

  P2_STAGE(0, 0);
#pragma unroll 1
  for (int kb = 0; kb < 16; ++kb) {
    const int cur = kb & 1;
    SBAR();
    if (kb < 15) {
      P2_STAGE(kb + 1, cur ^ 1);
      WAIT_VM6();
    } else {
      WAIT_VM0();
    }
    P2_FRAGS(cur);
    WAIT_LGKM0();
    P2_MFMA();
  }

  const int rg = lane >> 4;
#pragma unroll
  for (int f = 0; f < 4; ++f) {
#pragma unroll
    for (int r = 0; r < 4; ++r) {
      int ml = mb + f * 16 + rg * 4 + r;
      if (ml < valid) {
        int token = list[start + ml];
#pragma unroll
        for (int j = 0; j < 4; ++j) {
          int c = chunk * 256 + nb + j * 16 + col;
          atomicAdd(&out[(long)token * DDIM + c], acc[f][j][r]);
        }
      }
    }
  }
}

// ---------------------------------------------------------------------------
__global__ void loss_k(const float* __restrict__ accum, float* __restrict__ out) {
  if (threadIdx.x == 0 && blockIdx.x == 0) {
    float L = 0.f;
#pragma unroll
    for (int e = 0; e < 8; ++e) L += accum[e] * accum[8 + e];
    out[0] = L * 8.f / ((float)T_TOK * (float)T_TOK);
  }
}

// ---------------------------------------------------------------------------
extern "C" void kernel_launch(void* const* d_in, const int* in_sizes, int n_in,
                              void* d_out, int out_size, void* d_ws,
                              size_t ws_size, hipStream_t stream) {
  const float* x     = (const float*)d_in[0];
  const float* gatew = (const float*)d_in[1];
  const float* gw    = (const float*)d_in[2];
  const float* pw    = (const float*)d_in[3];
  const float* ow    = (const float*)d_in[4];

  float* out       = (float*)d_out;
  float* logitsOut = out + (long)T_TOK * DDIM;
  float* lossOut   = out + (long)T_TOK * DDIM + T_TOK * 8;

  char* wsB = (char*)d_ws;
  float*  accum  = (float*)wsB;
  int*    cursor = (int*)(wsB + 64);
  int*    offs   = (int*)(wsB + 96);
  float4* route  = (float4*)(wsB + 1024);
  int*    list   = (int*)(wsB + 263168);
  float*  wsl    = (float*)(wsB + 394240);
  char*   wg     = wsB + (1l << 20);
  char*   wp     = wsB + 17825792;
  char*   wo     = wsB + 34603008;
  char*   hw     = wsB + 51380224;                          // 64 MiB
  unsigned short* xb = (unsigned short*)(wsB + 118489088);  // 32 MiB
  const bool big = ws_size >= 152043520ul;

  hipMemsetAsync(d_out, 0, (size_t)out_size * 4, stream);
  hipMemsetAsync(accum, 0, 64, stream);
  convert_k<<<dim3(16, 16, 24), 256, 0, stream>>>(gw, pw, ow, wg, wp, wo);
  router_k<<<256, 256, 0, stream>>>(x, gatew, logitsOut, route, accum,
                                    big ? xb : nullptr);
  offsets_k<<<1, 64, 0, stream>>>(accum, offs, cursor);
  scatter_k<<<64, 256, 0, stream>>>(route, cursor, list, wsl);
  if (big)
    pass1_k<1><<<dim3(1024, 8), 512, 0, stream>>>(x, xb, wg, wp, list, wsl,
                                                  offs, hw);
  else
    pass1_k<0><<<dim3(1024, 8), 512, 0, stream>>>(x, xb, wg, wp, list, wsl,
                                                  offs, hw);
  pass2_k<<<dim3(1024, 4), 512, 0, stream>>>(hw, wo, list, offs, out);
  loss_k<<<1, 64, 0, stream>>>(accum, lossOut);
}

// Round 7
// 694.897 us; speedup vs baseline: 1.0825x; 1.0825x over previous
//
#include <hip/hip_runtime.h>
#include <hip/hip_bf16.h>
#include <cstdint>

// Instance: B=4,S=4096 -> T=16384, D=1024, E=8, H=1024, top_k=2. f32 in/out.
#define T_TOK 16384
#define DDIM  1024

typedef __attribute__((ext_vector_type(8))) short bf16x8;
typedef __attribute__((ext_vector_type(4))) float f32x4;

__device__ __forceinline__ unsigned short f2bf(float f) {
  unsigned u = __builtin_bit_cast(unsigned, f);
  return (unsigned short)((u + 0x7fffu + ((u >> 16) & 1u)) >> 16);  // RNE
}
__device__ __forceinline__ unsigned pk2(float a, float b) {
  return (unsigned)f2bf(a) | ((unsigned)f2bf(b) << 16);
}
__device__ __forceinline__ void gload16(const void* g, void* l) {
  typedef __attribute__((address_space(1))) const unsigned int gu32;
  typedef __attribute__((address_space(3))) unsigned int lu32;
  __builtin_amdgcn_global_load_lds((gu32*)g, (lu32*)l, 16, 0, 0);
}

#define SBAR()                        \
  __builtin_amdgcn_sched_barrier(0);  \
  __builtin_amdgcn_s_barrier();       \
  __builtin_amdgcn_sched_barrier(0)
#define WAIT_VM8()                                        \
  asm volatile("s_waitcnt vmcnt(8)" ::: "memory");        \
  __builtin_amdgcn_sched_barrier(0)
#define WAIT_VM0()                                        \
  asm volatile("s_waitcnt vmcnt(0)" ::: "memory");        \
  __builtin_amdgcn_sched_barrier(0)

// ---------------------------------------------------------------------------
// Transpose-convert weights f32->bf16 (unchanged, verified).
// ---------------------------------------------------------------------------
__global__ __launch_bounds__(256) void convert_k(
    const float* __restrict__ gw, const float* __restrict__ pw,
    const float* __restrict__ ow, char* __restrict__ wg,
    char* __restrict__ wp, char* __restrict__ wo) {
  __shared__ float t[64][65];
  const int z = blockIdx.z;
  const int arr = z >> 3, e = z & 7;
  const float* src = (arr == 0 ? gw : arr == 1 ? pw : ow) + ((long)e << 20);
  char* dst = (arr == 0 ? wg : arr == 1 ? wp : wo) + ((long)e << 21);
  const int r0 = blockIdx.x * 64, c0 = blockIdx.y * 64;
  const int row = threadIdx.x >> 2, q = threadIdx.x & 3;
  const float4* sp = (const float4*)(src + (long)(r0 + row) * 1024 + c0 + q * 16);
  float4 v0 = sp[0], v1 = sp[1], v2 = sp[2], v3 = sp[3];
  float* tr = &t[row][q * 16];
  tr[0]=v0.x; tr[1]=v0.y; tr[2]=v0.z; tr[3]=v0.w;
  tr[4]=v1.x; tr[5]=v1.y; tr[6]=v1.z; tr[7]=v1.w;
  tr[8]=v2.x; tr[9]=v2.y; tr[10]=v2.z; tr[11]=v2.w;
  tr[12]=v3.x; tr[13]=v3.y; tr[14]=v3.z; tr[15]=v3.w;
  __syncthreads();
  const int cl = row, rq = q;
  uint4 o0, o1;
  o0.x = pk2(t[rq*16+ 0][cl], t[rq*16+ 1][cl]);
  o0.y = pk2(t[rq*16+ 2][cl], t[rq*16+ 3][cl]);
  o0.z = pk2(t[rq*16+ 4][cl], t[rq*16+ 5][cl]);
  o0.w = pk2(t[rq*16+ 6][cl], t[rq*16+ 7][cl]);
  o1.x = pk2(t[rq*16+ 8][cl], t[rq*16+ 9][cl]);
  o1.y = pk2(t[rq*16+10][cl], t[rq*16+11][cl]);
  o1.z = pk2(t[rq*16+12][cl], t[rq*16+13][cl]);
  o1.w = pk2(t[rq*16+14][cl], t[rq*16+15][cl]);
  char* dp = dst + (long)(c0 + cl) * 2048 + (long)(r0 + rq * 16) * 2;
  *(uint4*)dp = o0;
  *(uint4*)(dp + 16) = o1;
}

// ---------------------------------------------------------------------------
// Router (unchanged, verified).
// ---------------------------------------------------------------------------
__global__ __launch_bounds__(256) void router_k(
    const float* __restrict__ x, const float* __restrict__ gatew,
    float* __restrict__ logitsOut, float4* __restrict__ route,
    float* __restrict__ accum, unsigned short* __restrict__ xbo) {
  __shared__ float accB[16];
  const int tid = threadIdx.x;
  if (tid < 16) accB[tid] = 0.f;
  __syncthreads();
  const int lane = tid & 63;
  const int gwave = blockIdx.x * 4 + (tid >> 6);

  for (int g = gwave; g < 4096; g += 1024) {
    const int t0 = g * 4;
    float s[4][8];
#pragma unroll
    for (int tt = 0; tt < 4; ++tt)
#pragma unroll
      for (int e = 0; e < 8; ++e) s[tt][e] = 0.f;

    for (int i = 0; i < 16; ++i) {
      int d = lane + i * 64;
      float4 w0 = *(const float4*)(gatew + d * 8);
      float4 w1 = *(const float4*)(gatew + d * 8 + 4);
#pragma unroll
      for (int tt = 0; tt < 4; ++tt) {
        float xv = x[(long)(t0 + tt) * DDIM + d];
        if (xbo) xbo[(long)(t0 + tt) * DDIM + d] = f2bf(xv);
        s[tt][0] += xv * w0.x; s[tt][1] += xv * w0.y;
        s[tt][2] += xv * w0.z; s[tt][3] += xv * w0.w;
        s[tt][4] += xv * w1.x; s[tt][5] += xv * w1.y;
        s[tt][6] += xv * w1.z; s[tt][7] += xv * w1.w;
      }
    }
#pragma unroll
    for (int m = 1; m < 64; m <<= 1)
#pragma unroll
      for (int tt = 0; tt < 4; ++tt)
#pragma unroll
        for (int e = 0; e < 8; ++e) s[tt][e] += __shfl_xor(s[tt][e], m);

    float psum[8];
#pragma unroll
    for (int e = 0; e < 8; ++e) psum[e] = 0.f;
    int i1a[4], i2a[4];
    float w1a[4], w2a[4];
#pragma unroll
    for (int tt = 0; tt < 4; ++tt) {
      float mx = s[tt][0];
#pragma unroll
      for (int e = 1; e < 8; ++e) mx = fmaxf(mx, s[tt][e]);
      float pe[8], Z = 0.f;
#pragma unroll
      for (int e = 0; e < 8; ++e) { pe[e] = __expf(s[tt][e] - mx); Z += pe[e]; }
      float inv = 1.f / Z;
#pragma unroll
      for (int e = 0; e < 8; ++e) { pe[e] *= inv; psum[e] += pe[e]; }
      int i1 = 0; float p1 = pe[0];
#pragma unroll
      for (int e = 1; e < 8; ++e) if (pe[e] > p1) { p1 = pe[e]; i1 = e; }
      int i2 = -1; float p2 = -1.f;
#pragma unroll
      for (int e = 0; e < 8; ++e)
        if (e != i1 && pe[e] > p2) { p2 = pe[e]; i2 = e; }
      float wsum = p1 + p2;
      i1a[tt] = i1; i2a[tt] = i2;
      w1a[tt] = p1 / wsum; w2a[tt] = p2 / wsum;
    }
    if (lane < 32) {
      int tt = lane >> 3, e = lane & 7;
      logitsOut[(t0 + tt) * 8 + e] = s[tt][e];
    }
    if (lane < 32 && (lane & 7) == 0) {
      int tt = lane >> 3;
      float4 rr;
      rr.x = w1a[tt]; rr.y = w2a[tt];
      rr.z = __int_as_float(i1a[tt]); rr.w = __int_as_float(i2a[tt]);
      route[t0 + tt] = rr;
    }
    if (lane < 8) {
      float c = 0.f;
#pragma unroll
      for (int tt = 0; tt < 4; ++tt)
        c += (float)(i1a[tt] == lane) + (float)(i2a[tt] == lane);
      atomicAdd(&accB[lane], psum[lane]);
      atomicAdd(&accB[8 + lane], c);
    }
  }
  __syncthreads();
  if (tid < 16) atomicAdd(&accum[tid], accB[tid]);
}

// ---------------------------------------------------------------------------
__global__ void offsets_k(const float* __restrict__ accum,
                          int* __restrict__ offs, int* __restrict__ cursor) {
  if (threadIdx.x == 0) {
    int c = 0;
#pragma unroll
    for (int e = 0; e < 8; ++e) {
      offs[e] = c; cursor[e] = c;
      c += (int)(accum[8 + e] + 0.5f);
    }
    offs[8] = c;
  }
}

__global__ __launch_bounds__(256) void scatter_k(
    const float4* __restrict__ route, int* __restrict__ cursor,
    int* __restrict__ list, float* __restrict__ wsl) {
  int t = blockIdx.x * 256 + threadIdx.x;
  float4 rr = route[t];
  int i1 = __float_as_int(rr.z), i2 = __float_as_int(rr.w);
  int s1 = atomicAdd(&cursor[i1], 1);
  list[s1] = t; wsl[s1] = rr.x;
  int s2 = atomicAdd(&cursor[i2], 1);
  list[s2] = t; wsl[s2] = rr.y;
}

// ---------------------------------------------------------------------------
// Pass 1 grouped GEMM. Block tile 256 slots x 128 h-cols (g+p), 8 waves as
// 2m x 4n -> wave tile 128m x (32g+32p). 1.5x less LDS frag traffic per FLOP
// vs the 128-slot tile (LDS-BW was the round-6 binding limit).
// Schedule: single-barrier dbuf, counted vmcnt(8), setprio around MFMA.
// ---------------------------------------------------------------------------
template <int XB>
__global__ __launch_bounds__(512, 2) void pass1_k(
    const float* __restrict__ x, const unsigned short* __restrict__ xb,
    const char* __restrict__ wg, const char* __restrict__ wp,
    const int* __restrict__ list, const float* __restrict__ wsl,
    const int* __restrict__ offs, char* __restrict__ hw) {
  __shared__ __align__(16) char Al[2][32768];
  __shared__ __align__(16) char Bgl[2][16384];
  __shared__ __align__(16) char Bpl[2][16384];
  const int e = blockIdx.x & 7, tile = blockIdx.x >> 3;  // XCD-aware decode
  const int s0 = offs[e], s1 = offs[e + 1];
  const int start = s0 + tile * 256;
  if (start >= s1) return;
  const int valid = min(256, s1 - start);
  const int chunk = blockIdx.y;  // h-cols chunk*128
  const int tid = threadIdx.x, lane = tid & 63, wid = tid >> 6;

  const int l8 = lane >> 3, seg = lane & 7;
  const unsigned inrow = ((unsigned)(seg * 16)) ^ (((unsigned)l8) << 4);

  // A staging: 4 insts/wave, rows wid*32 + i*8 + l8 (gathered tokens)
  const char* asrc[4];
  unsigned adst[4];
#pragma unroll
  for (int i = 0; i < 4; ++i) {
    int row = wid * 32 + i * 8 + l8;
    int tok = list[start + min(row, valid - 1)];
    asrc[i] = (const char*)xb + ((long)tok << 11) + inrow;
    adst[i] = (unsigned)(wid * 4096 + i * 1024);
  }
  // B staging: 2+2 insts/wave, h-rows wid*16 + i*8 + l8
  const long wbase = ((long)e << 21) + ((long)(chunk * 128) << 11);
  const char* gsrc[2];
  const char* psrc[2];
  unsigned bdst[2];
#pragma unroll
  for (int i = 0; i < 2; ++i) {
    int h = wid * 16 + i * 8 + l8;
    gsrc[i] = wg + wbase + ((long)h << 11) + inrow;
    psrc[i] = wp + wbase + ((long)h << 11) + inrow;
    bdst[i] = (unsigned)(wid * 2048 + i * 1024);
  }

  f32x4 aG[8][2], aP[8][2];
#pragma unroll
  for (int f = 0; f < 8; ++f)
#pragma unroll
    for (int j = 0; j < 2; ++j) {
      aG[f][j] = (f32x4){0.f, 0.f, 0.f, 0.f};
      aP[f][j] = (f32x4){0.f, 0.f, 0.f, 0.f};
    }

  const int col = lane & 15, kg = lane >> 4;
  const int mb = (wid >> 2) * 128, nb = (wid & 3) * 32;

#define P1_STAGE(kb, buf)                                     \
  {                                                           \
    long ko = (long)(kb) << 7;                                \
    gload16(asrc[0] + ko, &Al[buf][adst[0]]);                 \
    gload16(asrc[1] + ko, &Al[buf][adst[1]]);                 \
    gload16(asrc[2] + ko, &Al[buf][adst[2]]);                 \
    gload16(asrc[3] + ko, &Al[buf][adst[3]]);                 \
    gload16(gsrc[0] + ko, &Bgl[buf][bdst[0]]);                \
    gload16(gsrc[1] + ko, &Bgl[buf][bdst[1]]);                \
    gload16(psrc[0] + ko, &Bpl[buf][bdst[0]]);                \
    gload16(psrc[1] + ko, &Bpl[buf][bdst[1]]);                \
  }
#define P1_COMPUTE(cur)                                                     \
  _Pragma("unroll") for (int ks = 0; ks < 2; ++ks) {                        \
    bf16x8 bg[2], bp[2];                                                    \
    _Pragma("unroll") for (int j = 0; j < 2; ++j) {                         \
      int n = nb + j * 16 + col;                                            \
      unsigned off = (unsigned)(n * 128 + ks * 64 + kg * 16) ^              \
                     (((unsigned)n & 7u) << 4);                             \
      bg[j] = *(const bf16x8*)(&Bgl[cur][0] + off);                         \
      bp[j] = *(const bf16x8*)(&Bpl[cur][0] + off);                         \
    }                                                                       \
    _Pragma("unroll") for (int f = 0; f < 8; ++f) {                         \
      int r = mb + f * 16 + col;                                            \
      bf16x8 a = *(const bf16x8*)(                                          \
          &Al[cur][0] + ((unsigned)(r * 128 + ks * 64 + kg * 16) ^          \
                         (((unsigned)r & 7u) << 4)));                       \
      _Pragma("unroll") for (int j = 0; j < 2; ++j) {                       \
        aG[f][j] = __builtin_amdgcn_mfma_f32_16x16x32_bf16(a, bg[j],        \
                                                           aG[f][j], 0, 0, 0); \
        aP[f][j] = __builtin_amdgcn_mfma_f32_16x16x32_bf16(a, bp[j],        \
                                                           aP[f][j], 0, 0, 0); \
      }                                                                     \
    }                                                                       \
  }

  if (XB) {
    P1_STAGE(0, 0);
#pragma unroll 1
    for (int kb = 0; kb < 16; ++kb) {
      const int cur = kb & 1;
      SBAR();  // all waves done reading buf[cur^1] -> refill ok
      if (kb < 15) {
        P1_STAGE(kb + 1, cur ^ 1);
        WAIT_VM8();  // stage kb landed; the 8 just-issued stay in flight
      } else {
        WAIT_VM0();
      }
      __builtin_amdgcn_s_setprio(1);
      P1_COMPUTE(cur);
      __builtin_amdgcn_s_setprio(0);
    }
  } else {
    // Fallback (ws too small for xb): 2-phase, f32 reg-staged A, single buf.
    const int sr2 = tid >> 1, q2 = tid & 1;
    const int tokS = list[start + min(sr2, valid - 1)];
    const float* axp = x + (long)tokS * DDIM + q2 * 32;
    const unsigned swzS = ((unsigned)(sr2 & 7)) << 4;
    const unsigned sbS = (unsigned)(sr2 * 128 + q2 * 64);
    for (int kb = 0; kb < 16; ++kb) {
      __syncthreads();
      {
        const float4* ap = (const float4*)(axp + kb * 64);
#pragma unroll
        for (int m = 0; m < 4; ++m) {
          float4 v0 = ap[m * 2], v1 = ap[m * 2 + 1];
          uint4 w;
          w.x = pk2(v0.x, v0.y); w.y = pk2(v0.z, v0.w);
          w.z = pk2(v1.x, v1.y); w.w = pk2(v1.z, v1.w);
          *(uint4*)(&Al[0][0] + ((sbS + m * 16) ^ swzS)) = w;
        }
        long ko = (long)kb << 7;
        gload16(gsrc[0] + ko, &Bgl[0][bdst[0]]);
        gload16(gsrc[1] + ko, &Bgl[0][bdst[1]]);
        gload16(psrc[0] + ko, &Bpl[0][bdst[0]]);
        gload16(psrc[1] + ko, &Bpl[0][bdst[1]]);
      }
      __syncthreads();
      P1_COMPUTE(0);
    }
  }

  const int rg = lane >> 4;
#pragma unroll
  for (int f = 0; f < 8; ++f) {
#pragma unroll
    for (int r = 0; r < 4; ++r) {
      int ml = mb + f * 16 + rg * 4 + r;
      if (ml < valid) {
        int slot = start + ml;
        float wv = wsl[slot];
#pragma unroll
        for (int j = 0; j < 2; ++j) {
          float g = aG[f][j][r], p = aP[f][j][r];
          float h = g * (p / (1.f + __expf(-p))) * wv;
          int hc = chunk * 128 + nb + j * 16 + col;
          *(unsigned short*)(hw + (((long)slot << 11) + (hc << 1))) = f2bf(h);
        }
      }
    }
  }
}

// ---------------------------------------------------------------------------
// Pass 2 grouped GEMM. Block tile 256 slots x 256 d-cols, 8 waves 2m x 4n ->
// wave 128 x 64. Same pipeline; atomicAdd epilogue (2 commuting adds/elem).
// ---------------------------------------------------------------------------
__global__ __launch_bounds__(512, 2) void pass2_k(
    const char* __restrict__ hw, const char* __restrict__ wo,
    const int* __restrict__ list, const int* __restrict__ offs,
    float* __restrict__ out) {
  __shared__ __align__(16) char Al[2][32768];
  __shared__ __align__(16) char Bl[2][32768];
  const int e = blockIdx.x & 7, tile = blockIdx.x >> 3;
  const int s0 = offs[e], s1 = offs[e + 1];
  const int start = s0 + tile * 256;
  if (start >= s1) return;
  const int valid = min(256, s1 - start);
  const int chunk = blockIdx.y;  // d-cols chunk*256
  const int tid = threadIdx.x, lane = tid & 63, wid = tid >> 6;

  const int l8 = lane >> 3, seg = lane & 7;
  const unsigned inrow = ((unsigned)(seg * 16)) ^ (((unsigned)l8) << 4);

  const char* asrc[4];
  const char* bsrc[4];
  unsigned dst4[4];
#pragma unroll
  for (int i = 0; i < 4; ++i) {
    int row = wid * 32 + i * 8 + l8;
    asrc[i] = hw + ((long)(start + min(row, valid - 1)) << 11) + inrow;
    int n = wid * 32 + i * 8 + l8;
    bsrc[i] = wo + ((long)e << 21) + ((long)(chunk * 256 + n) << 11) + inrow;
    dst4[i] = (unsigned)(wid * 4096 + i * 1024);
  }

  f32x4 acc[8][4];
#pragma unroll
  for (int f = 0; f < 8; ++f)
#pragma unroll
    for (int j = 0; j < 4; ++j) acc[f][j] = (f32x4){0.f, 0.f, 0.f, 0.f};

  const int col = lane & 15, kg = lane >> 4;
  const int mb = (wid >> 2) * 128, nb = (wid & 3) * 64;

#define P2_STAGE(kb, buf)                                     \
  {                                                           \
    long ko = (long)(kb) << 7;                                \
    gload16(asrc[0] + ko, &Al[buf][dst4[0]]);                 \
    gload16(asrc[1] + ko, &Al[buf][dst4[1]]);                 \
    gload16(asrc[2] + ko, &Al[buf][dst4[2]]);                 \
    gload16(asrc[3] + ko, &Al[buf][dst4[3]]);                 \
    gload16(bsrc[0] + ko, &Bl[buf][dst4[0]]);                 \
    gload16(bsrc[1] + ko, &Bl[buf][dst4[1]]);                 \
    gload16(bsrc[2] + ko, &Bl[buf][dst4[2]]);                 \
    gload16(bsrc[3] + ko, &Bl[buf][dst4[3]]);                 \
  }

  P2_STAGE(0, 0);
#pragma unroll 1
  for (int kb = 0; kb < 16; ++kb) {
    const int cur = kb & 1;
    SBAR();
    if (kb < 15) {
      P2_STAGE(kb + 1, cur ^ 1);
      WAIT_VM8();
    } else {
      WAIT_VM0();
    }
    __builtin_amdgcn_s_setprio(1);
#pragma unroll
    for (int ks = 0; ks < 2; ++ks) {
      bf16x8 bf4[4];
#pragma unroll
      for (int j = 0; j < 4; ++j) {
        int n = nb + j * 16 + col;
        bf4[j] = *(const bf16x8*)(
            &Bl[cur][0] + ((unsigned)(n * 128 + ks * 64 + kg * 16) ^
                           (((unsigned)n & 7u) << 4)));
      }
#pragma unroll
      for (int f = 0; f < 8; ++f) {
        int r = mb + f * 16 + col;
        bf16x8 a = *(const bf16x8*)(
            &Al[cur][0] + ((unsigned)(r * 128 + ks * 64 + kg * 16) ^
                           (((unsigned)r & 7u) << 4)));
#pragma unroll
        for (int j = 0; j < 4; ++j)
          acc[f][j] = __builtin_amdgcn_mfma_f32_16x16x32_bf16(a, bf4[j],
                                                              acc[f][j], 0, 0, 0);
      }
    }
    __builtin_amdgcn_s_setprio(0);
  }

  const int rg = lane >> 4;
#pragma unroll
  for (int f = 0; f < 8; ++f) {
#pragma unroll
    for (int r = 0; r < 4; ++r) {
      int ml = mb + f * 16 + rg * 4 + r;
      if (ml < valid) {
        int token = list[start + ml];
#pragma unroll
        for (int j = 0; j < 4; ++j) {
          int c = chunk * 256 + nb + j * 16 + col;
          atomicAdd(&out[(long)token * DDIM + c], acc[f][j][r]);
        }
      }
    }
  }
}

// ---------------------------------------------------------------------------
__global__ void loss_k(const float* __restrict__ accum, float* __restrict__ out) {
  if (threadIdx.x == 0 && blockIdx.x == 0) {
    float L = 0.f;
#pragma unroll
    for (int e = 0; e < 8; ++e) L += accum[e] * accum[8 + e];
    out[0] = L * 8.f / ((float)T_TOK * (float)T_TOK);
  }
}

// ---------------------------------------------------------------------------
extern "C" void kernel_launch(void* const* d_in, const int* in_sizes, int n_in,
                              void* d_out, int out_size, void* d_ws,
                              size_t ws_size, hipStream_t stream) {
  const float* x     = (const float*)d_in[0];
  const float* gatew = (const float*)d_in[1];
  const float* gw    = (const float*)d_in[2];
  const float* pw    = (const float*)d_in[3];
  const float* ow    = (const float*)d_in[4];

  float* out       = (float*)d_out;
  float* logitsOut = out + (long)T_TOK * DDIM;
  float* lossOut   = out + (long)T_TOK * DDIM + T_TOK * 8;

  char* wsB = (char*)d_ws;
  float*  accum  = (float*)wsB;
  int*    cursor = (int*)(wsB + 64);
  int*    offs   = (int*)(wsB + 96);
  float4* route  = (float4*)(wsB + 1024);
  int*    list   = (int*)(wsB + 263168);
  float*  wsl    = (float*)(wsB + 394240);
  char*   wg     = wsB + (1l << 20);
  char*   wp     = wsB + 17825792;
  char*   wo     = wsB + 34603008;
  char*   hw     = wsB + 51380224;                          // 64 MiB
  unsigned short* xb = (unsigned short*)(wsB + 118489088);  // 32 MiB
  const bool big = ws_size >= 152043520ul;

  hipMemsetAsync(d_out, 0, (size_t)out_size * 4, stream);
  hipMemsetAsync(accum, 0, 64, stream);
  convert_k<<<dim3(16, 16, 24), 256, 0, stream>>>(gw, pw, ow, wg, wp, wo);
  router_k<<<256, 256, 0, stream>>>(x, gatew, logitsOut, route, accum,
                                    big ? xb : nullptr);
  offsets_k<<<1, 64, 0, stream>>>(accum, offs, cursor);
  scatter_k<<<64, 256, 0, stream>>>(route, cursor, list, wsl);
  if (big)
    pass1_k<1><<<dim3(512, 8), 512, 0, stream>>>(x, xb, wg, wp, list, wsl,
                                                 offs, hw);
  else
    pass1_k<0><<<dim3(512, 8), 512, 0, stream>>>(x, xb, wg, wp, list, wsl,
                                                 offs, hw);
  pass2_k<<<dim3(512, 4), 512, 0, stream>>>(hw, wo, list, offs, out);
  loss_k<<<1, 64, 0, stream>>>(accum, lossOut);
}